// Round 1
// baseline (332.312 us; speedup 1.0000x reference)
//
#include <hip/hip_runtime.h>

// Problem constants (from reference):
//   D = 8388608 elements, N = M = 1024 (power of two -> mod == AND)
// Outputs concatenated in d_out (float32):
//   [0,      D)      phase_out  (as float)
//   [D,     2D)      mag_out    (as float)
//   [2D,    3D)      signal
//   [3D]             strength   (scalar)
//   [3D+1,  4D+1)    grad_phase   <- base misaligned by 4B
//   [4D+1,  5D+1)    grad_mag     <- same
//
// Two-kernel design (round-1 structure, kept): main kernel writes the 5
// streams + per-block partial sums to d_ws; a 1-block kernel reduces the
// partials. Round 2's fused last-block-done pattern regressed 5x (device-
// scope atomics on one cache line across 8 XCDs serialize ~55ns each).
//
// R4 (this round) theory: rocprof top-5 shows only the harness's 640MiB
// poison fills (~102us each); main is therefore <100us and dur_us=290.7
// implies main ~80us = 3.8 TB/s on 302 MB of mandatory traffic -- ~60% of
// the 6.3+ TB/s the fills themselves achieve. Suspects: (a) idx loads
// program-ordered after LDS staging + barrier (hipcc can't hoist across
// s_barrier) -> block-start latency exposure; (b) ~90 live VGPRs -> 5
// waves/SIMD. Fix: issue idx loads first, store po/mo early, compute
// signal/grads in 4-element halves (peak live ~60 VGPRs), nt hints on all
// pure-streaming traffic. Summation order unchanged (strength bitwise-stable).
constexpr int D_TOTAL = 8388608;
constexpr int TBL = 1024;
constexpr int IDX_MASK = 1023;
constexpr int BLOCK = 256;
constexpr int VEC = 8;                        // elements per thread
constexpr int ELEMS_PER_BLOCK = BLOCK * VEC;  // 2048
constexpr int NBLOCKS = D_TOTAL / ELEMS_PER_BLOCK;  // 4096

typedef float f32x4 __attribute__((ext_vector_type(4)));
typedef float f32x8 __attribute__((ext_vector_type(8)));
typedef int   i32x8 __attribute__((ext_vector_type(8)));
// 4-byte-aligned float4: grad sections start at 3D+1/4D+1 (4B off 16B).
// global_store_dwordx4 only needs dword alignment in HW; this typedef lets
// clang emit it instead of 4 scalar stores.
typedef f32x4 f32x4u __attribute__((aligned(4)));

__global__ __launch_bounds__(BLOCK) void phasecell_main(
    const int* __restrict__ ctx_p, const int* __restrict__ ctx_m,
    const int* __restrict__ self_p, const int* __restrict__ self_m,
    const float* __restrict__ cos_t, const float* __restrict__ exp_t,
    const float* __restrict__ dcos_t, const float* __restrict__ dexp_t,
    float* __restrict__ out, float* __restrict__ block_sums) {
  const int base = (blockIdx.x * BLOCK + threadIdx.x) * VEC;

  // Issue the 4 streaming idx loads FIRST (~900-cycle HBM latency) so they
  // overlap table staging + the barrier instead of starting after them.
  // nt: zero reuse -> don't let 128 MiB of idx churn L2/L3.
  const i32x8 cp =
      __builtin_nontemporal_load(reinterpret_cast<const i32x8*>(ctx_p + base));
  const i32x8 cm =
      __builtin_nontemporal_load(reinterpret_cast<const i32x8*>(ctx_m + base));
  const i32x8 sp =
      __builtin_nontemporal_load(reinterpret_cast<const i32x8*>(self_p + base));
  const i32x8 sm =
      __builtin_nontemporal_load(reinterpret_cast<const i32x8*>(self_m + base));

  // Stage interleaved tables in LDS: one ds_read_b64 per gather.
  // (Measured r2: ~5 conflict-cycles/gather -> ~4us total. Not a bottleneck.)
  __shared__ float2 s_phase[TBL];  // (cos, dcos)
  __shared__ float2 s_mag[TBL];    // (exp, dexp)
  for (int i = threadIdx.x; i < TBL; i += BLOCK) {
    s_phase[i] = make_float2(cos_t[i], dcos_t[i]);
    s_mag[i]   = make_float2(exp_t[i], dexp_t[i]);
  }
  __syncthreads();

  int p[VEC], m[VEC];
#pragma unroll
  for (int j = 0; j < VEC; ++j) {
    p[j] = (cp[j] + sp[j]) & IDX_MASK;
    m[j] = (cm[j] + sm[j]) & IDX_MASK;
  }

  // Store phase_out/mag_out immediately: frees cp/cm/sp/sm + po/mo registers
  // before the gather/multiply phase (occupancy).
  f32x8 po, mo;
#pragma unroll
  for (int j = 0; j < VEC; ++j) {
    po[j] = (float)p[j];
    mo[j] = (float)m[j];
  }
  __builtin_nontemporal_store(po, reinterpret_cast<f32x8*>(out + base));
  __builtin_nontemporal_store(mo, reinterpret_cast<f32x8*>(out + D_TOTAL + base));

  float* sig_base = out + 2 * D_TOTAL + base;       // 32B aligned
  float* gp_base  = out + 3 * D_TOTAL + 1 + base;   // 4B aligned
  float* gm_base  = out + 4 * D_TOTAL + 1 + base;   // 4B aligned

  // Signal + grads in two 4-element halves, storing per half: peak live
  // float state = 12 regs instead of 40. Accumulation order over j is
  // IDENTICAL to the previous verified kernel (strength bitwise-stable).
  float local = 0.f;
#pragma unroll
  for (int h = 0; h < 2; ++h) {
    f32x4 sg, gp, gm;
#pragma unroll
    for (int j = 0; j < 4; ++j) {
      const int e = h * 4 + j;                 // compile-time after unroll
      const float2 ph = s_phase[p[e]];
      const float2 mg = s_mag[m[e]];
      sg[j] = ph.x * mg.x;
      gp[j] = ph.y * mg.x;
      gm[j] = ph.x * mg.y;
      local += sg[j];
    }
    __builtin_nontemporal_store(sg, reinterpret_cast<f32x4*>(sig_base + h * 4));
    __builtin_nontemporal_store(gp, reinterpret_cast<f32x4u*>(gp_base + h * 4));
    __builtin_nontemporal_store(gm, reinterpret_cast<f32x4u*>(gm_base + h * 4));
  }

  // Block reduction of `local` -> block_sums[blockIdx.x] (deterministic,
  // same order as previous verified kernel).
#pragma unroll
  for (int off = 32; off > 0; off >>= 1) local += __shfl_down(local, off, 64);
  __shared__ float wsum[BLOCK / 64];
  const int wave = threadIdx.x >> 6;
  const int lane = threadIdx.x & 63;
  if (lane == 0) wsum[wave] = local;
  __syncthreads();
  if (threadIdx.x == 0) {
    float t = 0.f;
#pragma unroll
    for (int w = 0; w < BLOCK / 64; ++w) t += wsum[w];
    block_sums[blockIdx.x] = t;
  }
}

__global__ __launch_bounds__(BLOCK) void phasecell_reduce(
    const float* __restrict__ partials, float* __restrict__ strength_out) {
  float s = 0.f;
  for (int i = threadIdx.x; i < NBLOCKS; i += BLOCK) s += partials[i];
#pragma unroll
  for (int off = 32; off > 0; off >>= 1) s += __shfl_down(s, off, 64);
  __shared__ float wsum[BLOCK / 64];
  const int wave = threadIdx.x >> 6;
  const int lane = threadIdx.x & 63;
  if (lane == 0) wsum[wave] = s;
  __syncthreads();
  if (threadIdx.x == 0) {
    float t = 0.f;
#pragma unroll
    for (int w = 0; w < BLOCK / 64; ++w) t += wsum[w];
    strength_out[0] = t;  // out[3D]
  }
}

extern "C" void kernel_launch(void* const* d_in, const int* in_sizes, int n_in,
                              void* d_out, int out_size, void* d_ws, size_t ws_size,
                              hipStream_t stream) {
  const int* ctx_p  = (const int*)d_in[0];
  const int* ctx_m  = (const int*)d_in[1];
  const int* self_p = (const int*)d_in[2];
  const int* self_m = (const int*)d_in[3];
  const float* cos_t  = (const float*)d_in[4];
  const float* exp_t  = (const float*)d_in[5];
  const float* dcos_t = (const float*)d_in[6];
  const float* dexp_t = (const float*)d_in[7];
  float* out = (float*)d_out;
  float* block_sums = (float*)d_ws;  // NBLOCKS floats = 16 KB

  phasecell_main<<<NBLOCKS, BLOCK, 0, stream>>>(
      ctx_p, ctx_m, self_p, self_m, cos_t, exp_t, dcos_t, dexp_t, out, block_sums);
  phasecell_reduce<<<1, BLOCK, 0, stream>>>(block_sums, out + 3 * (size_t)D_TOTAL);
}

// Round 2
// 308.482 us; speedup vs baseline: 1.0772x; 1.0772x over previous
//
#include <hip/hip_runtime.h>

// Problem constants (from reference):
//   D = 8388608 elements, N = M = 1024 (power of two -> mod == AND)
// Outputs concatenated in d_out (float32):
//   [0,      D)      phase_out  (as float)
//   [D,     2D)      mag_out    (as float)
//   [2D,    3D)      signal
//   [3D]             strength   (scalar)
//   [3D+1,  4D+1)    grad_phase   <- base misaligned by 4B
//   [4D+1,  5D+1)    grad_mag     <- same
//
// Two-kernel design (kept): main kernel writes the 5 streams + per-block
// partial sums to d_ws; a 1-block kernel reduces the partials. The fused
// atomic variant regressed 5x (device-scope atomics on one line across
// 8 XCDs). Never again.
//
// R2 history: all-nt variant (R1) regressed main 85->116us. rocprof:
// WRITE_SIZE 297.6 MB vs 167.8 mandatory -- nt disables L2 write-combining,
// so 16B sig halves (half-sector) and 4B-misaligned 16B grad stores
// (sector-straddling) each go out as full 32B sector writes => ~+130 MB.
// Fix (this round):
//   - grads: REGULAR stores (L2 merges partial sectors into full lines)
//   - sig:   one aligned 32B f32x8 nt store (full sector; no-allocate
//            preserves L3 residency of the 134 MB input set)
//   - po/mo: 32B nt stores (full sector), unchanged
//   - idx:   regular loads (allocate in L3 -> cross-iteration reuse)
// Keep: early-issued idx loads (latency hides under LDS staging+barrier),
// half-split gather phase (VGPR=28, occupancy not a limiter), identical
// summation order (strength bitwise-stable, absmax 0.0 two rounds running).
constexpr int D_TOTAL = 8388608;
constexpr int TBL = 1024;
constexpr int IDX_MASK = 1023;
constexpr int BLOCK = 256;
constexpr int VEC = 8;                        // elements per thread
constexpr int ELEMS_PER_BLOCK = BLOCK * VEC;  // 2048
constexpr int NBLOCKS = D_TOTAL / ELEMS_PER_BLOCK;  // 4096

typedef float f32x4 __attribute__((ext_vector_type(4)));
typedef float f32x8 __attribute__((ext_vector_type(8)));
typedef int   i32x8 __attribute__((ext_vector_type(8)));
// 4-byte-aligned vectors: grad sections start at 3D+1/4D+1 (4B off 16B).
// global_store_dwordx4 only needs dword alignment in HW; these typedefs let
// clang emit dwordx4 pairs instead of scalar stores.
typedef f32x4 f32x4u __attribute__((aligned(4)));
typedef f32x8 f32x8u __attribute__((aligned(4)));

__global__ __launch_bounds__(BLOCK) void phasecell_main(
    const int* __restrict__ ctx_p, const int* __restrict__ ctx_m,
    const int* __restrict__ self_p, const int* __restrict__ self_m,
    const float* __restrict__ cos_t, const float* __restrict__ exp_t,
    const float* __restrict__ dcos_t, const float* __restrict__ dexp_t,
    float* __restrict__ out, float* __restrict__ block_sums) {
  const int base = (blockIdx.x * BLOCK + threadIdx.x) * VEC;

  // Issue the 4 streaming idx loads FIRST (~900-cycle HBM latency) so they
  // overlap table staging + the barrier. Regular loads: allocate in L3 so
  // inputs (134 MB) stay resident across graph iterations.
  const i32x8 cp = *reinterpret_cast<const i32x8*>(ctx_p + base);
  const i32x8 cm = *reinterpret_cast<const i32x8*>(ctx_m + base);
  const i32x8 sp = *reinterpret_cast<const i32x8*>(self_p + base);
  const i32x8 sm = *reinterpret_cast<const i32x8*>(self_m + base);

  // Stage interleaved tables in LDS: one ds_read_b64 per gather.
  // (Measured: ~2% of cycles in bank conflicts. Not a bottleneck.)
  __shared__ float2 s_phase[TBL];  // (cos, dcos)
  __shared__ float2 s_mag[TBL];    // (exp, dexp)
  for (int i = threadIdx.x; i < TBL; i += BLOCK) {
    s_phase[i] = make_float2(cos_t[i], dcos_t[i]);
    s_mag[i]   = make_float2(exp_t[i], dexp_t[i]);
  }
  __syncthreads();

  int p[VEC], m[VEC];
#pragma unroll
  for (int j = 0; j < VEC; ++j) {
    p[j] = (cp[j] + sp[j]) & IDX_MASK;
    m[j] = (cm[j] + sm[j]) & IDX_MASK;
  }

  // Store phase_out/mag_out immediately: frees cp/cm/sp/sm + po/mo registers
  // before the gather/multiply phase. 32B-aligned full-sector nt stores.
  f32x8 po, mo;
#pragma unroll
  for (int j = 0; j < VEC; ++j) {
    po[j] = (float)p[j];
    mo[j] = (float)m[j];
  }
  __builtin_nontemporal_store(po, reinterpret_cast<f32x8*>(out + base));
  __builtin_nontemporal_store(mo, reinterpret_cast<f32x8*>(out + D_TOTAL + base));

  float* sig_base = out + 2 * D_TOTAL + base;       // 32B aligned
  float* gp_base  = out + 3 * D_TOTAL + 1 + base;   // 4B aligned
  float* gm_base  = out + 4 * D_TOTAL + 1 + base;   // 4B aligned

  // Gather + multiply. Accumulation order over j=0..7 is IDENTICAL to the
  // verified kernels (strength bitwise-stable).
  f32x8 sg;
  f32x8u gp, gm;
  float local = 0.f;
#pragma unroll
  for (int j = 0; j < VEC; ++j) {
    const float2 ph = s_phase[p[j]];
    const float2 mg = s_mag[m[j]];
    sg[j] = ph.x * mg.x;
    gp[j] = ph.y * mg.x;
    gm[j] = ph.x * mg.y;
    local += sg[j];
  }

  // sig: one aligned 32B nt store (full sector -> no amplification).
  __builtin_nontemporal_store(sg, reinterpret_cast<f32x8*>(sig_base));
  // grads: REGULAR stores -- must pass through L2 write-combining so the
  // 4B-misaligned partial sectors merge into full lines (R1 lesson:
  // nt here = +130 MB WRITE_SIZE).
  *reinterpret_cast<f32x8u*>(gp_base) = gp;
  *reinterpret_cast<f32x8u*>(gm_base) = gm;

  // Block reduction of `local` -> block_sums[blockIdx.x] (deterministic,
  // same order as previous verified kernels).
#pragma unroll
  for (int off = 32; off > 0; off >>= 1) local += __shfl_down(local, off, 64);
  __shared__ float wsum[BLOCK / 64];
  const int wave = threadIdx.x >> 6;
  const int lane = threadIdx.x & 63;
  if (lane == 0) wsum[wave] = local;
  __syncthreads();
  if (threadIdx.x == 0) {
    float t = 0.f;
#pragma unroll
    for (int w = 0; w < BLOCK / 64; ++w) t += wsum[w];
    block_sums[blockIdx.x] = t;
  }
}

__global__ __launch_bounds__(BLOCK) void phasecell_reduce(
    const float* __restrict__ partials, float* __restrict__ strength_out) {
  float s = 0.f;
  for (int i = threadIdx.x; i < NBLOCKS; i += BLOCK) s += partials[i];
#pragma unroll
  for (int off = 32; off > 0; off >>= 1) s += __shfl_down(s, off, 64);
  __shared__ float wsum[BLOCK / 64];
  const int wave = threadIdx.x >> 6;
  const int lane = threadIdx.x & 63;
  if (lane == 0) wsum[wave] = s;
  __syncthreads();
  if (threadIdx.x == 0) {
    float t = 0.f;
#pragma unroll
    for (int w = 0; w < BLOCK / 64; ++w) t += wsum[w];
    strength_out[0] = t;  // out[3D]
  }
}

extern "C" void kernel_launch(void* const* d_in, const int* in_sizes, int n_in,
                              void* d_out, int out_size, void* d_ws, size_t ws_size,
                              hipStream_t stream) {
  const int* ctx_p  = (const int*)d_in[0];
  const int* ctx_m  = (const int*)d_in[1];
  const int* self_p = (const int*)d_in[2];
  const int* self_m = (const int*)d_in[3];
  const float* cos_t  = (const float*)d_in[4];
  const float* exp_t  = (const float*)d_in[5];
  const float* dcos_t = (const float*)d_in[6];
  const float* dexp_t = (const float*)d_in[7];
  float* out = (float*)d_out;
  float* block_sums = (float*)d_ws;  // NBLOCKS floats = 16 KB

  phasecell_main<<<NBLOCKS, BLOCK, 0, stream>>>(
      ctx_p, ctx_m, self_p, self_m, cos_t, exp_t, dcos_t, dexp_t, out, block_sums);
  phasecell_reduce<<<1, BLOCK, 0, stream>>>(block_sums, out + 3 * (size_t)D_TOTAL);
}

// Round 3
// 288.691 us; speedup vs baseline: 1.1511x; 1.0686x over previous
//
#include <hip/hip_runtime.h>

// Problem constants (from reference):
//   D = 8388608 elements, N = M = 1024 (power of two -> mod == AND)
// Outputs concatenated in d_out (float32):
//   [0,      D)      phase_out  (as float)
//   [D,     2D)      mag_out    (as float)
//   [2D,    3D)      signal
//   [3D]             strength   (scalar)
//   [3D+1,  4D+1)    grad_phase   <- section base misaligned by 4B
//   [4D+1,  5D+1)    grad_mag     <- same
//
// Two-kernel design (kept): main writes 5 streams + per-block partials to
// d_ws; 1-block kernel reduces. Fused atomic variant regressed 5x. Never.
//
// Optimization history:
//  R0 (best): all regular stores, misaligned f32x8 grad stores. main ~82us.
//  R1: all-nontemporal -> WRITE 297.6 MB vs 167.8 mandatory. nt defeats L2
//      write-merging; partial sectors go to HBM as full 32B writes. main 116.
//  R2: nt only on po/mo/sig -> WRITE 220 MB, main 107. Confirms EVERY nt
//      store stream costs; reverted to all-regular here.
//  R3 (this): the misaligned grad stores are the remaining anomaly. FETCH
//      was 65.7 MB in a kernel whose inputs are L3-resident -- signature of
//      partial-line RMW fills: each wave's 4B-offset 2048B grad region
//      leaves partially-written 128B lines at wave boundaries; dirty
//      partial evictions force HBM read-modify-write. Fix: shift store
//      slots by +1 so grad vectors land 32B-aligned (slot s holds element
//      s-1). Neighbor values via __shfl_up (already-computed, bitwise
//      identical); wave boundary via LDS; block boundary via 4-scalar
//      re-gather (bitwise identical recompute). Head (7 floats) / tail
//      (1 float) of each grad stream handled specially. Arithmetic and
//      reduction order UNCHANGED -> all outputs bitwise stable.
constexpr int D_TOTAL = 8388608;
constexpr int TBL = 1024;
constexpr int IDX_MASK = 1023;
constexpr int BLOCK = 256;
constexpr int VEC = 8;                        // elements per thread
constexpr int ELEMS_PER_BLOCK = BLOCK * VEC;  // 2048
constexpr int NBLOCKS = D_TOTAL / ELEMS_PER_BLOCK;  // 4096

typedef float f32x4 __attribute__((ext_vector_type(4)));
typedef float f32x8 __attribute__((ext_vector_type(8)));
typedef int   i32x8 __attribute__((ext_vector_type(8)));
typedef float f32x2 __attribute__((ext_vector_type(2)));

__global__ __launch_bounds__(BLOCK) void phasecell_main(
    const int* __restrict__ ctx_p, const int* __restrict__ ctx_m,
    const int* __restrict__ self_p, const int* __restrict__ self_m,
    const float* __restrict__ cos_t, const float* __restrict__ exp_t,
    const float* __restrict__ dcos_t, const float* __restrict__ dexp_t,
    float* __restrict__ out, float* __restrict__ block_sums) {
  const int base = (blockIdx.x * BLOCK + threadIdx.x) * VEC;

  // Block-boundary neighbor: thread 0 of blocks >0 re-gathers element
  // base-1. Issue the 4 scalar loads FIRST so their latency hides under
  // staging (1 thread/block; exec-masked, negligible traffic).
  int cpp = 0, spp = 0, cpm = 0, spm = 0;
  const bool need_prev = (threadIdx.x == 0) && (blockIdx.x != 0);
  if (need_prev) {
    cpp = ctx_p[base - 1];  spp = self_p[base - 1];
    cpm = ctx_m[base - 1];  spm = self_m[base - 1];
  }

  // Stage interleaved tables in LDS: one ds_read_b64 per gather.
  __shared__ float2 s_phase[TBL];  // (cos, dcos)
  __shared__ float2 s_mag[TBL];    // (exp, dexp)
  for (int i = threadIdx.x; i < TBL; i += BLOCK) {
    s_phase[i] = make_float2(cos_t[i], dcos_t[i]);
    s_mag[i]   = make_float2(exp_t[i], dexp_t[i]);
  }
  __syncthreads();

  // Regular (allocating) vector loads: idx set is L3-resident across iters.
  const i32x8 cp = *reinterpret_cast<const i32x8*>(ctx_p + base);
  const i32x8 cm = *reinterpret_cast<const i32x8*>(ctx_m + base);
  const i32x8 sp = *reinterpret_cast<const i32x8*>(self_p + base);
  const i32x8 sm = *reinterpret_cast<const i32x8*>(self_m + base);

  int p[VEC], m[VEC];
#pragma unroll
  for (int j = 0; j < VEC; ++j) {
    p[j] = (cp[j] + sp[j]) & IDX_MASK;
    m[j] = (cm[j] + sm[j]) & IDX_MASK;
  }

  // Gather + multiply. Accumulation order over j=0..7 IDENTICAL to all
  // previous verified kernels (strength bitwise-stable).
  f32x8 po, mo, sg;
  float gpv[VEC], gmv[VEC];
  float local = 0.f;
#pragma unroll
  for (int j = 0; j < VEC; ++j) {
    const float2 ph = s_phase[p[j]];
    const float2 mg = s_mag[m[j]];
    const float s = ph.x * mg.x;
    sg[j] = s;
    gpv[j] = ph.y * mg.x;
    gmv[j] = ph.x * mg.y;
    po[j] = (float)p[j];
    mo[j] = (float)m[j];
    local += s;
  }

  // Aligned sections: regular 32B stores (L2 write-combining active).
  *reinterpret_cast<f32x8*>(out + base)               = po;
  *reinterpret_cast<f32x8*>(out + D_TOTAL + base)     = mo;
  *reinterpret_cast<f32x8*>(out + 2 * D_TOTAL + base) = sg;

  // ---- Aligned grad stores: slot s (address sectionBase-1 + s) holds
  // element s-1. Thread covers slots [base, base+8) at out+3D+base /
  // out+4D+base, both 32B-aligned. Needs element base-1's grads:
  float pgp = __shfl_up(gpv[VEC - 1], 1);  // lane L <- lane L-1 (64-wide)
  float pgm = __shfl_up(gmv[VEC - 1], 1);
  __shared__ float wlast_gp[BLOCK / 64], wlast_gm[BLOCK / 64];
  const int wave = threadIdx.x >> 6;
  const int lane = threadIdx.x & 63;
  if (lane == 63) { wlast_gp[wave] = gpv[VEC - 1]; wlast_gm[wave] = gmv[VEC - 1]; }
  __syncthreads();
  if (lane == 0) {
    if (wave > 0) {
      pgp = wlast_gp[wave - 1];
      pgm = wlast_gm[wave - 1];
    } else if (blockIdx.x != 0) {
      // Re-gather element base-1 (bitwise-identical recompute).
      const int pp = (cpp + spp) & IDX_MASK;
      const int pm = (cpm + spm) & IDX_MASK;
      const float2 ph = s_phase[pp];
      const float2 mg = s_mag[pm];
      pgp = ph.y * mg.x;
      pgm = ph.x * mg.y;
    }
  }

  f32x8 gpo, gmo;
  gpo[0] = pgp;  gmo[0] = pgm;
#pragma unroll
  for (int j = 1; j < VEC; ++j) { gpo[j] = gpv[j - 1]; gmo[j] = gmv[j - 1]; }

  if (base != 0) {
    *reinterpret_cast<f32x8*>(out + 3 * D_TOTAL + base) = gpo;  // 32B aligned
    *reinterpret_cast<f32x8*>(out + 4 * D_TOTAL + base) = gmo;  // 32B aligned
  } else {
    // Head of each grad stream: elements 0..6 at sectionBase..sectionBase+6.
    // Split 1 + 2 + 4 on natural alignment (3D+1 scalar, 3D+2 8B, 3D+4 16B).
    float* g0 = out + 3 * D_TOTAL;
    float* g1 = out + 4 * D_TOTAL;
    g0[1] = gpo[1];
    g1[1] = gmo[1];
    *reinterpret_cast<f32x2*>(g0 + 2) = f32x2{gpo[2], gpo[3]};
    *reinterpret_cast<f32x2*>(g1 + 2) = f32x2{gmo[2], gmo[3]};
    *reinterpret_cast<f32x4*>(g0 + 4) = f32x4{gpo[4], gpo[5], gpo[6], gpo[7]};
    *reinterpret_cast<f32x4*>(g1 + 4) = f32x4{gmo[4], gmo[5], gmo[6], gmo[7]};
  }
  if (base == D_TOTAL - VEC) {
    // Tail: global element D-1 -> out[4D] (grad_phase), out[5D] (grad_mag).
    out[4 * D_TOTAL] = gpv[VEC - 1];
    out[5 * D_TOTAL] = gmv[VEC - 1];
  }

  // Block reduction of `local` -> block_sums[blockIdx.x] (deterministic,
  // same order as previous verified kernels).
#pragma unroll
  for (int off = 32; off > 0; off >>= 1) local += __shfl_down(local, off, 64);
  __shared__ float wsum[BLOCK / 64];
  if (lane == 0) wsum[wave] = local;
  __syncthreads();
  if (threadIdx.x == 0) {
    float t = 0.f;
#pragma unroll
    for (int w = 0; w < BLOCK / 64; ++w) t += wsum[w];
    block_sums[blockIdx.x] = t;
  }
}

__global__ __launch_bounds__(BLOCK) void phasecell_reduce(
    const float* __restrict__ partials, float* __restrict__ strength_out) {
  float s = 0.f;
  for (int i = threadIdx.x; i < NBLOCKS; i += BLOCK) s += partials[i];
#pragma unroll
  for (int off = 32; off > 0; off >>= 1) s += __shfl_down(s, off, 64);
  __shared__ float wsum[BLOCK / 64];
  const int wave = threadIdx.x >> 6;
  const int lane = threadIdx.x & 63;
  if (lane == 0) wsum[wave] = s;
  __syncthreads();
  if (threadIdx.x == 0) {
    float t = 0.f;
#pragma unroll
    for (int w = 0; w < BLOCK / 64; ++w) t += wsum[w];
    strength_out[0] = t;  // out[3D]
  }
}

extern "C" void kernel_launch(void* const* d_in, const int* in_sizes, int n_in,
                              void* d_out, int out_size, void* d_ws, size_t ws_size,
                              hipStream_t stream) {
  const int* ctx_p  = (const int*)d_in[0];
  const int* ctx_m  = (const int*)d_in[1];
  const int* self_p = (const int*)d_in[2];
  const int* self_m = (const int*)d_in[3];
  const float* cos_t  = (const float*)d_in[4];
  const float* exp_t  = (const float*)d_in[5];
  const float* dcos_t = (const float*)d_in[6];
  const float* dexp_t = (const float*)d_in[7];
  float* out = (float*)d_out;
  float* block_sums = (float*)d_ws;  // NBLOCKS floats = 16 KB

  phasecell_main<<<NBLOCKS, BLOCK, 0, stream>>>(
      ctx_p, ctx_m, self_p, self_m, cos_t, exp_t, dcos_t, dexp_t, out, block_sums);
  phasecell_reduce<<<1, BLOCK, 0, stream>>>(block_sums, out + 3 * (size_t)D_TOTAL);
}